// Round 1
// baseline (1365.866 us; speedup 1.0000x reference)
//
#include <hip/hip_runtime.h>
#include <hip/hip_bf16.h>
#include <cfloat>

#define DEV static __device__ __forceinline__

constexpr int NP_ = 400000;
constexpr int NV_ = 2000;
constexpr int D_  = 256;
constexpr int H_  = 8;

typedef __attribute__((ext_vector_type(8))) short bf16x8;
typedef __attribute__((ext_vector_type(4))) float f32x4;

DEV unsigned short f2bf(float f) {
  unsigned u = __float_as_uint(f);
  u += 0x7FFFu + ((u >> 16) & 1u);   // round-to-nearest-even
  return (unsigned short)(u >> 16);
}
DEV float bf2f(unsigned short h) { return __uint_as_float(((unsigned)h) << 16); }
DEV unsigned fmap(float f) {        // monotone float->uint for atomicMax
  unsigned u = __float_as_uint(f);
  return (u & 0x80000000u) ? ~u : (u | 0x80000000u);
}
DEV float funmap(unsigned u) {
  return __uint_as_float((u & 0x80000000u) ? (u & 0x7FFFFFFFu) : ~u);
}

DEV float blockSum256(float v, float* red) {
  int t = threadIdx.x;
  #pragma unroll
  for (int o = 32; o > 0; o >>= 1) v += __shfl_down(v, o);
  __syncthreads();
  if ((t & 63) == 0) red[t >> 6] = v;
  __syncthreads();
  return red[0] + red[1] + red[2] + red[3];
}

// ---------------- init ----------------
__global__ void k_init(unsigned* mseg, float* sseg, int* cnt) {
  int i = blockIdx.x * 256 + threadIdx.x;
  if (i < NV_ * H_) { mseg[i] = fmap(-FLT_MAX); sseg[i] = 0.f; }
  if (i < NV_) cnt[i] = 0;
}

// ---------------- view prep: xr = relu(LN(prev)) @ Wr^T + br ----------------
__global__ __launch_bounds__(256) void k_view(const float* __restrict__ prev,
    const float* __restrict__ Wr, const float* __restrict__ br,
    const float* __restrict__ g1, const float* __restrict__ b1,
    float* __restrict__ xr) {
  __shared__ float ysh[D_];
  __shared__ float red[4];
  int v = blockIdx.x, t = threadIdx.x;
  float x = prev[v * D_ + t];
  float s1 = blockSum256(x, red);
  float s2 = blockSum256(x * x, red);
  float mean = s1 * (1.f / D_);
  float var = s2 * (1.f / D_) - mean * mean;
  float y = (x - mean) * rsqrtf(var + 1e-5f) * g1[t] + b1[t];
  ysh[t] = fmaxf(y, 0.f);
  __syncthreads();
  float acc = 0.f;
  const float* wp = Wr + (size_t)t * D_;
  for (int k = 0; k < D_; k += 4) {
    float4 w = *(const float4*)(wp + k);
    acc += ysh[k] * w.x + ysh[k + 1] * w.y + ysh[k + 2] * w.z + ysh[k + 3] * w.w;
  }
  xr[v * D_ + t] = acc + br[t];
}

// ---------------- main GEMM + logits + segment max ----------------
// 128 edge-rows per block, 4 waves, each wave: 2 M-tiles x 16 N-tiles, K=256 in 8 steps.
__global__ __launch_bounds__(256) void k_gemm(const float* __restrict__ proj,
    const float* __restrict__ Wl, const float* __restrict__ bl,
    const float* __restrict__ att, const int* __restrict__ esrc,
    const int* __restrict__ edst, const float* __restrict__ xr,
    unsigned short* __restrict__ xl, float* __restrict__ logitsA,
    unsigned* __restrict__ mseg) {
  __shared__ unsigned short wlds[256 * 40];  // [n][k] bf16, padded stride 40 (2-way banks = free)
  const int t = threadIdx.x;
  const int wave = t >> 6, lane = t & 63;
  const int l15 = lane & 15, l4 = lane >> 4;
  const int wbase = blockIdx.x * 128 + wave * 32;

  const int srcs0 = esrc[wbase + l15];
  const int srcs1 = esrc[wbase + 16 + l15];

  f32x4 acc[2][16];
  #pragma unroll
  for (int mt = 0; mt < 2; ++mt)
    #pragma unroll
    for (int nt = 0; nt < 16; ++nt)
      acc[mt][nt] = (f32x4){0.f, 0.f, 0.f, 0.f};

  for (int ks = 0; ks < 8; ++ks) {
    const int k0 = ks * 32;
    __syncthreads();
    {  // stage Wl[n=t][k0..k0+31] -> bf16 LDS
      const float* wp = Wl + (size_t)t * D_ + k0;
      #pragma unroll
      for (int i = 0; i < 32; i += 8) {
        float4 w0 = *(const float4*)(wp + i);
        float4 w1 = *(const float4*)(wp + i + 4);
        bf16x8 pk;
        pk[0] = (short)f2bf(w0.x); pk[1] = (short)f2bf(w0.y);
        pk[2] = (short)f2bf(w0.z); pk[3] = (short)f2bf(w0.w);
        pk[4] = (short)f2bf(w1.x); pk[5] = (short)f2bf(w1.y);
        pk[6] = (short)f2bf(w1.z); pk[7] = (short)f2bf(w1.w);
        *(bf16x8*)(&wlds[t * 40 + i]) = pk;
      }
    }
    __syncthreads();
    bf16x8 a[2];
    #pragma unroll
    for (int mt = 0; mt < 2; ++mt) {
      const float* ap = proj + (size_t)(mt ? srcs1 : srcs0) * D_ + k0 + l4 * 8;
      float4 v0 = *(const float4*)ap;
      float4 v1 = *(const float4*)(ap + 4);
      bf16x8 av;
      av[0] = (short)f2bf(v0.x); av[1] = (short)f2bf(v0.y);
      av[2] = (short)f2bf(v0.z); av[3] = (short)f2bf(v0.w);
      av[4] = (short)f2bf(v1.x); av[5] = (short)f2bf(v1.y);
      av[6] = (short)f2bf(v1.z); av[7] = (short)f2bf(v1.w);
      a[mt] = av;
    }
    #pragma unroll
    for (int nt = 0; nt < 16; ++nt) {
      bf16x8 b = *(const bf16x8*)(&wlds[(nt * 16 + l15) * 40 + l4 * 8]);
      acc[0][nt] = __builtin_amdgcn_mfma_f32_16x16x32_bf16(a[0], b, acc[0][nt], 0, 0, 0);
      acc[1][nt] = __builtin_amdgcn_mfma_f32_16x16x32_bf16(a[1], b, acc[1][nt], 0, 0, 0);
    }
  }

  // epilogue: + b_l, store xl (bf16), logits + segment max
  float attv[16], blv[16];
  #pragma unroll
  for (int nt = 0; nt < 16; ++nt) {
    attv[nt] = att[nt * 16 + l15];   // att flat [h*32+c] == [nt*16 + l15]
    blv[nt] = bl[nt * 16 + l15];
  }
  #pragma unroll
  for (int mt = 0; mt < 2; ++mt)
    #pragma unroll
    for (int nt = 0; nt < 16; ++nt)
      #pragma unroll
      for (int j = 0; j < 4; ++j)
        acc[mt][nt][j] += blv[nt];

  if (xl) {
    #pragma unroll
    for (int mt = 0; mt < 2; ++mt)
      #pragma unroll
      for (int j = 0; j < 4; ++j) {
        const int row = wbase + mt * 16 + l4 * 4 + j;
        unsigned short* xp = xl + (size_t)row * D_ + l15;
        #pragma unroll
        for (int nt = 0; nt < 16; ++nt) xp[nt * 16] = f2bf(acc[mt][nt][j]);
      }
  }

  #pragma unroll
  for (int mt = 0; mt < 2; ++mt) {
    #pragma unroll
    for (int j = 0; j < 4; ++j) {
      const int row = wbase + mt * 16 + l4 * 4 + j;
      const int dst = edst[row];
      const float* xrp = xr + (size_t)dst * D_;
      float lg[8];
      #pragma unroll
      for (int h = 0; h < 8; ++h) {
        float p = 0.f;
        #pragma unroll
        for (int q = 0; q < 2; ++q) {
          const int nt = 2 * h + q;
          float vv = acc[mt][nt][j] + xrp[nt * 16 + l15];
          vv = vv > 0.f ? vv : 0.2f * vv;
          p += vv * attv[nt];
        }
        p += __shfl_xor(p, 1);
        p += __shfl_xor(p, 2);
        p += __shfl_xor(p, 4);
        p += __shfl_xor(p, 8);
        lg[h] = p;
      }
      if (l15 == 0) {
        #pragma unroll
        for (int h = 0; h < 8; ++h) {
          logitsA[(size_t)row * 8 + h] = lg[h];
          atomicMax(&mseg[dst * 8 + h], fmap(lg[h]));
        }
      }
    }
  }
}

// ---------------- alpha numerators + segment sums + counts ----------------
__global__ __launch_bounds__(256) void k_alpha(float* __restrict__ logitsA,
    const int* __restrict__ edst, const unsigned* __restrict__ mseg,
    float* __restrict__ sseg, int* __restrict__ cnt) {
  int e = blockIdx.x * 256 + threadIdx.x;
  if (e >= NP_) return;
  int dst = edst[e];
  float4 l0 = *(float4*)(logitsA + (size_t)e * 8);
  float4 l1 = *(float4*)(logitsA + (size_t)e * 8 + 4);
  float a[8] = {l0.x, l0.y, l0.z, l0.w, l1.x, l1.y, l1.z, l1.w};
  #pragma unroll
  for (int h = 0; h < 8; ++h) {
    float m = funmap(mseg[dst * 8 + h]);
    a[h] = __expf(a[h] - m);
    atomicAdd(&sseg[dst * 8 + h], a[h]);
  }
  l0.x = a[0]; l0.y = a[1]; l0.z = a[2]; l0.w = a[3];
  l1.x = a[4]; l1.y = a[5]; l1.z = a[6]; l1.w = a[7];
  *(float4*)(logitsA + (size_t)e * 8) = l0;
  *(float4*)(logitsA + (size_t)e * 8 + 4) = l1;
  atomicAdd(&cnt[dst], 1);
}

// ---------------- exclusive scan of counts ----------------
__global__ __launch_bounds__(256) void k_scan(const int* __restrict__ cnt,
    int* __restrict__ offs, int* __restrict__ cursor) {
  __shared__ int tot[256];
  __shared__ int base[257];
  int t = threadIdx.x;
  int c[8];
  int s = 0;
  #pragma unroll
  for (int i = 0; i < 8; ++i) {
    int idx = t * 8 + i;
    c[i] = (idx < NV_) ? cnt[idx] : 0;
    s += c[i];
  }
  tot[t] = s;
  __syncthreads();
  if (t == 0) {
    int accu = 0;
    for (int i = 0; i < 256; ++i) { base[i] = accu; accu += tot[i]; }
    base[256] = accu;
  }
  __syncthreads();
  int run = base[t];
  #pragma unroll
  for (int i = 0; i < 8; ++i) {
    int idx = t * 8 + i;
    if (idx < NV_) { offs[idx] = run; cursor[idx] = run; run += c[i]; }
  }
  if (t == 0) offs[NV_] = base[256];
}

// ---------------- bucket edges by dst ----------------
__global__ __launch_bounds__(256) void k_scatter(const int* __restrict__ edst,
    int* __restrict__ cursor, int* __restrict__ elist) {
  int e = blockIdx.x * 256 + threadIdx.x;
  if (e >= NP_) return;
  int pos = atomicAdd(&cursor[edst[e]], 1);
  elist[pos] = e;
}

// ---------------- shared tail: residual + LN2 + relu + Wmlp + skip ----------------
DEV void ln_mlp_tail(int v, int t, float agg,
    const float* __restrict__ prev, const float* __restrict__ bias_gat,
    const float* __restrict__ g2, const float* __restrict__ b2,
    const float* __restrict__ Wmlp, const float* __restrict__ bmlp,
    float* __restrict__ out, float* ysh, float* red) {
  float xv = prev[v * D_ + t] + agg + bias_gat[t];
  float xskip = xv;
  float s1 = blockSum256(xv, red);
  float s2 = blockSum256(xv * xv, red);
  float mean = s1 * (1.f / D_);
  float var = s2 * (1.f / D_) - mean * mean;
  float y = (xv - mean) * rsqrtf(var + 1e-5f) * g2[t] + b2[t];
  ysh[t] = fmaxf(y, 0.f);
  __syncthreads();
  float acc = 0.f;
  const float* wp = Wmlp + (size_t)t * D_;
  for (int k = 0; k < D_; k += 4) {
    float4 w = *(const float4*)(wp + k);
    acc += ysh[k] * w.x + ysh[k + 1] * w.y + ysh[k + 2] * w.z + ysh[k + 3] * w.w;
  }
  out[v * D_ + t] = xskip + acc + bmlp[t];
}

// ---------------- aggregation (fast: reads materialized xl) ----------------
__global__ __launch_bounds__(256) void k_aggmlp(const unsigned short* __restrict__ xl,
    const float* __restrict__ logitsA, const float* __restrict__ sseg,
    const int* __restrict__ offs, const int* __restrict__ elist,
    const float* __restrict__ prev, const float* __restrict__ bias_gat,
    const float* __restrict__ g2, const float* __restrict__ b2,
    const float* __restrict__ Wmlp, const float* __restrict__ bmlp,
    float* __restrict__ out) {
  __shared__ float rcp_s[8];
  __shared__ int eids[64];
  __shared__ float wts[64 * 8];
  __shared__ float ysh[D_];
  __shared__ float red[4];
  int v = blockIdx.x, t = threadIdx.x;
  if (t < 8) { float s = sseg[v * 8 + t]; rcp_s[t] = (s > 0.f) ? 1.f / s : 0.f; }
  int e0 = offs[v], e1 = offs[v + 1];
  float agg = 0.f;
  const int h = t >> 5;
  for (int c0 = e0; c0 < e1; c0 += 64) {
    int n = min(64, e1 - c0);
    __syncthreads();
    if (t < n) eids[t] = elist[c0 + t];
    __syncthreads();
    for (int r = t; r < n * 8; r += 256)
      wts[r] = logitsA[(size_t)eids[r >> 3] * 8 + (r & 7)] * rcp_s[r & 7];
    __syncthreads();
    for (int i = 0; i < n; ++i)
      agg += bf2f(xl[(size_t)eids[i] * D_ + t]) * wts[i * 8 + h];
  }
  __syncthreads();
  ln_mlp_tail(v, t, agg, prev, bias_gat, g2, b2, Wmlp, bmlp, out, ysh, red);
}

// ---------------- aggregation fallback (recomputes xl; used only if ws too small) ----------------
__global__ __launch_bounds__(256) void k_aggmlp_slow(const float* __restrict__ proj,
    const float* __restrict__ Wl, const float* __restrict__ bl,
    const int* __restrict__ esrc,
    const float* __restrict__ logitsA, const float* __restrict__ sseg,
    const int* __restrict__ offs, const int* __restrict__ elist,
    const float* __restrict__ prev, const float* __restrict__ bias_gat,
    const float* __restrict__ g2, const float* __restrict__ b2,
    const float* __restrict__ Wmlp, const float* __restrict__ bmlp,
    float* __restrict__ out) {
  __shared__ float rows[16][260];
  __shared__ float rcp_s[8];
  __shared__ int eids[16];
  __shared__ float wts[16 * 8];
  __shared__ float ysh[D_];
  __shared__ float red[4];
  int v = blockIdx.x, t = threadIdx.x;
  if (t < 8) { float s = sseg[v * 8 + t]; rcp_s[t] = (s > 0.f) ? 1.f / s : 0.f; }
  int e0 = offs[v], e1 = offs[v + 1];
  float agg = 0.f;
  const int h = t >> 5;
  const float blv = bl[t];
  const float* wrow = Wl + (size_t)t * D_;
  for (int c0 = e0; c0 < e1; c0 += 16) {
    int n = min(16, e1 - c0);
    __syncthreads();
    if (t < n) eids[t] = elist[c0 + t];
    __syncthreads();
    {
      int i = t >> 4, kk = (t & 15) * 16;
      if (i < n) {
        const float* pr = proj + (size_t)esrc[eids[i]] * D_ + kk;
        #pragma unroll
        for (int q = 0; q < 16; q += 4)
          *(float4*)&rows[i][kk + q] = *(const float4*)(pr + q);
      }
    }
    for (int r = t; r < n * 8; r += 256)
      wts[r] = logitsA[(size_t)eids[r >> 3] * 8 + (r & 7)] * rcp_s[r & 7];
    __syncthreads();
    for (int i = 0; i < n; ++i) {
      float dot = 0.f;
      for (int k = 0; k < D_; k += 4) {
        float4 w = *(const float4*)(wrow + k);
        dot += rows[i][k] * w.x + rows[i][k + 1] * w.y + rows[i][k + 2] * w.z + rows[i][k + 3] * w.w;
      }
      agg += (dot + blv) * wts[i * 8 + h];
    }
  }
  __syncthreads();
  ln_mlp_tail(v, t, agg, prev, bias_gat, g2, b2, Wmlp, bmlp, out, ysh, red);
}

extern "C" void kernel_launch(void* const* d_in, const int* in_sizes, int n_in,
                              void* d_out, int out_size, void* d_ws, size_t ws_size,
                              hipStream_t stream) {
  const float* proj = (const float*)d_in[0];
  const float* prev = (const float*)d_in[1];
  const int* esrc = (const int*)d_in[2];
  const int* edst = (const int*)d_in[3];
  const float* Wl = (const float*)d_in[4];
  const float* bl = (const float*)d_in[5];
  const float* Wr = (const float*)d_in[6];
  const float* br = (const float*)d_in[7];
  const float* att = (const float*)d_in[8];
  const float* bias_gat = (const float*)d_in[9];
  const float* g1 = (const float*)d_in[10];
  const float* b1 = (const float*)d_in[11];
  const float* g2 = (const float*)d_in[12];
  const float* b2 = (const float*)d_in[13];
  const float* Wmlp = (const float*)d_in[14];
  const float* bmlp = (const float*)d_in[15];
  float* out = (float*)d_out;

  char* p = (char*)d_ws;
  size_t off = 0;
  auto carve = [&](size_t bytes) -> char* {
    char* q = p + off;
    off += (bytes + 255) & ~(size_t)255;
    return q;
  };
  float* xr = (float*)carve((size_t)NV_ * D_ * 4);
  float* logitsA = (float*)carve((size_t)NP_ * H_ * 4);
  unsigned* mseg = (unsigned*)carve((size_t)NV_ * H_ * 4);
  float* sseg = (float*)carve((size_t)NV_ * H_ * 4);
  int* cnt = (int*)carve((size_t)NV_ * 4);
  int* offs = (int*)carve((size_t)(NV_ + 1) * 4);
  int* cursor = (int*)carve((size_t)NV_ * 4);
  int* elist = (int*)carve((size_t)NP_ * 4);
  unsigned short* xl = (unsigned short*)carve((size_t)NP_ * D_ * 2);
  const bool fast = ws_size >= off;

  k_init<<<(NV_ * H_ + 255) / 256, 256, 0, stream>>>(mseg, sseg, cnt);
  k_view<<<NV_, 256, 0, stream>>>(prev, Wr, br, g1, b1, xr);
  k_gemm<<<NP_ / 128, 256, 0, stream>>>(proj, Wl, bl, att, esrc, edst, xr,
                                        fast ? xl : (unsigned short*)nullptr, logitsA, mseg);
  k_alpha<<<(NP_ + 255) / 256, 256, 0, stream>>>(logitsA, edst, mseg, sseg, cnt);
  k_scan<<<1, 256, 0, stream>>>(cnt, offs, cursor);
  k_scatter<<<(NP_ + 255) / 256, 256, 0, stream>>>(edst, cursor, elist);
  if (fast) {
    k_aggmlp<<<NV_, 256, 0, stream>>>(xl, logitsA, sseg, offs, elist, prev, bias_gat,
                                      g2, b2, Wmlp, bmlp, out);
  } else {
    k_aggmlp_slow<<<NV_, 256, 0, stream>>>(proj, Wl, bl, esrc, logitsA, sseg, offs, elist,
                                           prev, bias_gat, g2, b2, Wmlp, bmlp, out);
  }
}

// Round 5
// 900.381 us; speedup vs baseline: 1.5170x; 1.5170x over previous
//
#include <hip/hip_runtime.h>
#include <hip/hip_bf16.h>
#include <cfloat>

#define DEV static __device__ __forceinline__

constexpr int NP_ = 400000;
constexpr int NV_ = 2000;
constexpr int D_  = 256;
constexpr int H_  = 8;

typedef __attribute__((ext_vector_type(8))) short bf16x8;
typedef __attribute__((ext_vector_type(4))) float f32x4;

DEV unsigned short f2bf(float f) {
  unsigned u = __float_as_uint(f);
  u += 0x7FFFu + ((u >> 16) & 1u);   // round-to-nearest-even
  return (unsigned short)(u >> 16);
}
DEV float bf2f(unsigned short h) { return __uint_as_float(((unsigned)h) << 16); }

DEV void gll16(const void* g, void* l) {
  __builtin_amdgcn_global_load_lds(
      (const __attribute__((address_space(1))) unsigned int*)g,
      (__attribute__((address_space(3))) unsigned int*)l, 16, 0, 0);
}

DEV float blockSum256(float v, float* red) {
  int t = threadIdx.x;
  #pragma unroll
  for (int o = 32; o > 0; o >>= 1) v += __shfl_down(v, o);
  __syncthreads();
  if ((t & 63) == 0) red[t >> 6] = v;
  __syncthreads();
  return red[0] + red[1] + red[2] + red[3];
}

// ---------------- init: zero per-view edge counts ----------------
__global__ void k_init(int* cnt) {
  int i = blockIdx.x * 256 + threadIdx.x;
  if (i < NV_) cnt[i] = 0;
}

// ---------------- prep: Wl fp32 -> bf16, K-slice major, bank-swizzled ----------------
// For K-step ks, row n, k-quad q (k = ks*32 + q*8 .. +8):
//   wsB[ks*8192 + n*32 + (q ^ ((n>>1)&3))*8 .. +8]
__global__ __launch_bounds__(256) void k_prep(const float* __restrict__ Wl,
                                              unsigned short* __restrict__ wsB) {
  int tid = blockIdx.x * 256 + threadIdx.x;  // 0..8191
  int n = tid >> 5;
  int kq = tid & 31;
  int ks = kq >> 2, q = kq & 3;
  const float* wp = Wl + (size_t)n * D_ + kq * 8;
  float4 w0 = *(const float4*)wp;
  float4 w1 = *(const float4*)(wp + 4);
  bf16x8 pk;
  pk[0] = (short)f2bf(w0.x); pk[1] = (short)f2bf(w0.y);
  pk[2] = (short)f2bf(w0.z); pk[3] = (short)f2bf(w0.w);
  pk[4] = (short)f2bf(w1.x); pk[5] = (short)f2bf(w1.y);
  pk[6] = (short)f2bf(w1.z); pk[7] = (short)f2bf(w1.w);
  int slot = q ^ ((n >> 1) & 3);
  *(bf16x8*)(wsB + ks * 8192 + n * 32 + slot * 8) = pk;
}

// ---------------- view prep: xr = relu(LN(prev)) @ Wr^T + br ----------------
__global__ __launch_bounds__(256) void k_view(const float* __restrict__ prev,
    const float* __restrict__ Wr, const float* __restrict__ br,
    const float* __restrict__ g1, const float* __restrict__ b1,
    float* __restrict__ xr) {
  __shared__ float ysh[D_];
  __shared__ float red[4];
  int v = blockIdx.x, t = threadIdx.x;
  float x = prev[v * D_ + t];
  float s1 = blockSum256(x, red);
  float s2 = blockSum256(x * x, red);
  float mean = s1 * (1.f / D_);
  float var = s2 * (1.f / D_) - mean * mean;
  float y = (x - mean) * rsqrtf(var + 1e-5f) * g1[t] + b1[t];
  ysh[t] = fmaxf(y, 0.f);
  __syncthreads();
  float acc = 0.f;
  const float* wp = Wr + (size_t)t * D_;
  for (int k = 0; k < D_; k += 4) {
    float4 w = *(const float4*)(wp + k);
    acc += ysh[k] * w.x + ysh[k + 1] * w.y + ysh[k + 2] * w.z + ysh[k + 3] * w.w;
  }
  xr[v * D_ + t] = acc + br[t];
}

// ---------------- main GEMM + logits ----------------
// Block: 256 threads = 4 waves, 64 rows x 256 cols. Wave: 16 rows (mt=1, nt=16).
// acc[16] f32x4 = 64 regs -> 3 waves/SIMD target.
__global__ __launch_bounds__(256, 3) void k_gemm(const float* __restrict__ proj,
    const unsigned short* __restrict__ wsB, const float* __restrict__ bl,
    const float* __restrict__ att, const int* __restrict__ edst,
    const float* __restrict__ xr, unsigned short* __restrict__ xl,
    float* __restrict__ logitsA, int* __restrict__ cnt) {
  __shared__ unsigned short wlds[8448];  // staging 8192 + bounce pad (rows stride 264)
  const int t = threadIdx.x;
  const int wave = t >> 6, lane = t & 63;
  const int l15 = lane & 15, l4 = lane >> 4;
  const int rowBase = blockIdx.x * 64;
  const int wrow = rowBase + wave * 16;
  const int arow = wrow + l15;           // edge_src == arange -> A row == edge row

  f32x4 acc[16];
  #pragma unroll
  for (int nt = 0; nt < 16; ++nt) acc[nt] = (f32x4){0.f, 0.f, 0.f, 0.f};

  const float* abase = proj + (size_t)arow * D_ + l4 * 8;
  float4 a0 = *(const float4*)abase;
  float4 a1 = *(const float4*)(abase + 4);

  const int swz = (l15 >> 1) & 3;

  for (int ks = 0; ks < 8; ++ks) {
    __syncthreads();  // previous compute done -> LDS reusable
    {
      const unsigned short* gsrc = wsB + ks * 8192;
      #pragma unroll
      for (int i = 0; i < 4; ++i)
        gll16(gsrc + i * 2048 + t * 8, &wlds[i * 2048 + t * 8]);
    }
    bf16x8 af;
    af[0] = (short)f2bf(a0.x); af[1] = (short)f2bf(a0.y);
    af[2] = (short)f2bf(a0.z); af[3] = (short)f2bf(a0.w);
    af[4] = (short)f2bf(a1.x); af[5] = (short)f2bf(a1.y);
    af[6] = (short)f2bf(a1.z); af[7] = (short)f2bf(a1.w);
    if (ks < 7) {
      const float* ap = abase + (ks + 1) * 32;
      a0 = *(const float4*)ap;
      a1 = *(const float4*)(ap + 4);
    }
    __syncthreads();  // compiler drains vmcnt -> staged slice ready
    #pragma unroll
    for (int nt = 0; nt < 16; ++nt) {
      bf16x8 b = *(const bf16x8*)&wlds[(nt * 16 + l15) * 32 + ((l4 ^ swz) * 8)];
      acc[nt] = __builtin_amdgcn_mfma_f32_16x16x32_bf16(af, b, acc[nt], 0, 0, 0);
    }
  }

  // + b_l
  float attv[16], blv[16];
  #pragma unroll
  for (int nt = 0; nt < 16; ++nt) {
    attv[nt] = att[nt * 16 + l15];
    blv[nt] = bl[nt * 16 + l15];
  }
  #pragma unroll
  for (int nt = 0; nt < 16; ++nt)
    #pragma unroll
    for (int j = 0; j < 4; ++j) acc[nt][j] += blv[nt];

  // logits (store raw) + per-view edge count
  #pragma unroll
  for (int j = 0; j < 4; ++j) {
    const int row = wrow + l4 * 4 + j;
    const int dst = edst[row];
    const float* xrp = xr + (size_t)dst * D_;
    float lg[8];
    #pragma unroll
    for (int h = 0; h < 8; ++h) {
      float p = 0.f;
      #pragma unroll
      for (int q = 0; q < 2; ++q) {
        const int nt = 2 * h + q;
        float vv = acc[nt][j] + xrp[nt * 16 + l15];
        vv = vv > 0.f ? vv : 0.2f * vv;
        p += vv * attv[nt];
      }
      p += __shfl_xor(p, 1);
      p += __shfl_xor(p, 2);
      p += __shfl_xor(p, 4);
      p += __shfl_xor(p, 8);
      lg[h] = p;
    }
    if (l15 == 0) {
      #pragma unroll
      for (int h = 0; h < 8; ++h) logitsA[(size_t)row * 8 + h] = lg[h];
      atomicAdd(&cnt[dst], 1);
    }
  }

  // xl store via LDS bounce (32 rows per round, padded stride 264)
  if (xl) {
    #pragma unroll
    for (int r = 0; r < 2; ++r) {
      __syncthreads();
      if ((wave >> 1) == r) {
        const int lr0 = (wave & 1) * 16 + l4 * 4;
        #pragma unroll
        for (int j = 0; j < 4; ++j)
          #pragma unroll
          for (int nt = 0; nt < 16; ++nt)
            wlds[(lr0 + j) * 264 + nt * 16 + l15] = f2bf(acc[nt][j]);
      }
      __syncthreads();
      #pragma unroll
      for (int i = 0; i < 4; ++i) {
        const int el0 = (i * 256 + t) * 8;
        const int rl = el0 >> 8, col = el0 & 255;
        bf16x8 v = *(const bf16x8*)&wlds[rl * 264 + col];
        *(bf16x8*)(xl + (size_t)(rowBase + r * 32 + rl) * D_ + col) = v;
      }
    }
  }
}

// ---------------- exclusive scan of counts ----------------
__global__ __launch_bounds__(256) void k_scan(const int* __restrict__ cnt,
    int* __restrict__ offs, int* __restrict__ cursor) {
  __shared__ int tot[256];
  __shared__ int base[257];
  int t = threadIdx.x;
  int c[8];
  int s = 0;
  #pragma unroll
  for (int i = 0; i < 8; ++i) {
    int idx = t * 8 + i;
    c[i] = (idx < NV_) ? cnt[idx] : 0;
    s += c[i];
  }
  tot[t] = s;
  __syncthreads();
  if (t == 0) {
    int accu = 0;
    for (int i = 0; i < 256; ++i) { base[i] = accu; accu += tot[i]; }
    base[256] = accu;
  }
  __syncthreads();
  int run = base[t];
  #pragma unroll
  for (int i = 0; i < 8; ++i) {
    int idx = t * 8 + i;
    if (idx < NV_) { offs[idx] = run; cursor[idx] = run; run += c[i]; }
  }
  if (t == 0) offs[NV_] = base[256];
}

// ---------------- bucket edges by dst ----------------
__global__ __launch_bounds__(256) void k_scatter(const int* __restrict__ edst,
    int* __restrict__ cursor, int* __restrict__ elist) {
  int e = blockIdx.x * 256 + threadIdx.x;
  if (e >= NP_) return;
  int pos = atomicAdd(&cursor[edst[e]], 1);
  elist[pos] = e;
}

// ---------------- shared tail: residual + LN2 + relu + Wmlp + skip ----------------
DEV void ln_mlp_tail(int v, int t, float agg,
    const float* __restrict__ prev, const float* __restrict__ bias_gat,
    const float* __restrict__ g2, const float* __restrict__ b2,
    const float* __restrict__ Wmlp, const float* __restrict__ bmlp,
    float* __restrict__ out, float* ysh, float* red) {
  float xv = prev[v * D_ + t] + agg + bias_gat[t];
  float xskip = xv;
  float s1 = blockSum256(xv, red);
  float s2 = blockSum256(xv * xv, red);
  float mean = s1 * (1.f / D_);
  float var = s2 * (1.f / D_) - mean * mean;
  float y = (xv - mean) * rsqrtf(var + 1e-5f) * g2[t] + b2[t];
  ysh[t] = fmaxf(y, 0.f);
  __syncthreads();
  float acc = 0.f;
  const float* wp = Wmlp + (size_t)t * D_;
  for (int k = 0; k < D_; k += 4) {
    float4 w = *(const float4*)(wp + k);
    acc += ysh[k] * w.x + ysh[k + 1] * w.y + ysh[k + 2] * w.z + ysh[k + 3] * w.w;
  }
  out[v * D_ + t] = xskip + acc + bmlp[t];
}

// local (per-view) softmax over the sorted edge list: shared by fast & slow agg
#define LOCAL_SOFTMAX()                                                          \
  int e0 = offs[v], e1 = offs[v + 1], ne = e1 - e0;                              \
  {                                                                              \
    int h = t & 7, g = t >> 3;                                                   \
    float pm = -FLT_MAX;                                                         \
    for (int j = g; j < ne; j += 32)                                             \
      pm = fmaxf(pm, logitsA[(size_t)elist[e0 + j] * 8 + h]);                    \
    part[h * 33 + g] = pm;                                                       \
    __syncthreads();                                                             \
    if (t < 8) {                                                                 \
      float m = -FLT_MAX;                                                        \
      for (int i = 0; i < 32; ++i) m = fmaxf(m, part[t * 33 + i]);               \
      sm[t] = m;                                                                 \
    }                                                                            \
    __syncthreads();                                                             \
    float m = sm[h], ps = 0.f;                                                   \
    for (int j = g; j < ne; j += 32)                                             \
      ps += __expf(logitsA[(size_t)elist[e0 + j] * 8 + h] - m);                  \
    part[h * 33 + g] = ps;                                                       \
    __syncthreads();                                                             \
    if (t < 8) {                                                                 \
      float s = 0.f;                                                             \
      for (int i = 0; i < 32; ++i) s += part[t * 33 + i];                        \
      rcp[t] = s > 0.f ? 1.f / s : 0.f;                                          \
    }                                                                            \
    __syncthreads();                                                             \
  }

// ---------------- aggregation (fast: reads materialized xl) ----------------
__global__ __launch_bounds__(256) void k_aggmlp(const unsigned short* __restrict__ xl,
    const float* __restrict__ logitsA,
    const int* __restrict__ offs, const int* __restrict__ elist,
    const float* __restrict__ prev, const float* __restrict__ bias_gat,
    const float* __restrict__ g2, const float* __restrict__ b2,
    const float* __restrict__ Wmlp, const float* __restrict__ bmlp,
    float* __restrict__ out) {
  __shared__ float part[8 * 33];
  __shared__ float sm[8], rcp[8];
  __shared__ int eids[64];
  __shared__ float wts[64 * 8];
  __shared__ float ysh[D_];
  __shared__ float red[4];
  int v = blockIdx.x, t = threadIdx.x;
  LOCAL_SOFTMAX();
  float agg = 0.f;
  const int h3 = t >> 5;
  for (int c0 = 0; c0 < ne; c0 += 64) {
    int nn = min(64, ne - c0);
    __syncthreads();
    if (t < nn) eids[t] = elist[e0 + c0 + t];
    __syncthreads();
    for (int r = t; r < nn * 8; r += 256)
      wts[r] = __expf(logitsA[(size_t)eids[r >> 3] * 8 + (r & 7)] - sm[r & 7]) * rcp[r & 7];
    __syncthreads();
    int i = 0;
    for (; i + 4 <= nn; i += 4) {
      float x0 = bf2f(xl[(size_t)eids[i] * D_ + t]);
      float x1 = bf2f(xl[(size_t)eids[i + 1] * D_ + t]);
      float x2 = bf2f(xl[(size_t)eids[i + 2] * D_ + t]);
      float x3 = bf2f(xl[(size_t)eids[i + 3] * D_ + t]);
      agg += x0 * wts[i * 8 + h3];
      agg += x1 * wts[(i + 1) * 8 + h3];
      agg += x2 * wts[(i + 2) * 8 + h3];
      agg += x3 * wts[(i + 3) * 8 + h3];
    }
    for (; i < nn; ++i) agg += bf2f(xl[(size_t)eids[i] * D_ + t]) * wts[i * 8 + h3];
  }
  __syncthreads();
  ln_mlp_tail(v, t, agg, prev, bias_gat, g2, b2, Wmlp, bmlp, out, ysh, red);
}

// ---------------- aggregation fallback (recomputes xl rows; only if ws too small) ----------------
__global__ __launch_bounds__(256) void k_aggmlp_slow(const float* __restrict__ proj,
    const float* __restrict__ Wl, const float* __restrict__ bl,
    const int* __restrict__ esrc, const float* __restrict__ logitsA,
    const int* __restrict__ offs, const int* __restrict__ elist,
    const float* __restrict__ prev, const float* __restrict__ bias_gat,
    const float* __restrict__ g2, const float* __restrict__ b2,
    const float* __restrict__ Wmlp, const float* __restrict__ bmlp,
    float* __restrict__ out) {
  __shared__ float part[8 * 33];
  __shared__ float sm[8], rcp[8];
  __shared__ float rows[16][260];
  __shared__ int eids[16];
  __shared__ float wts[16 * 8];
  __shared__ float ysh[D_];
  __shared__ float red[4];
  int v = blockIdx.x, t = threadIdx.x;
  LOCAL_SOFTMAX();
  float agg = 0.f;
  const int h3 = t >> 5;
  const float blv = bl[t];
  const float* wrow = Wl + (size_t)t * D_;
  for (int c0 = 0; c0 < ne; c0 += 16) {
    int nn = min(16, ne - c0);
    __syncthreads();
    if (t < nn) eids[t] = elist[e0 + c0 + t];
    __syncthreads();
    {
      int i = t >> 4, kk = (t & 15) * 16;
      if (i < nn) {
        const float* pr = proj + (size_t)esrc[eids[i]] * D_ + kk;
        #pragma unroll
        for (int q = 0; q < 16; q += 4)
          *(float4*)&rows[i][kk + q] = *(const float4*)(pr + q);
      }
    }
    for (int r = t; r < nn * 8; r += 256)
      wts[r] = __expf(logitsA[(size_t)eids[r >> 3] * 8 + (r & 7)] - sm[r & 7]) * rcp[r & 7];
    __syncthreads();
    for (int i = 0; i < nn; ++i) {
      float dot = 0.f;
      for (int k = 0; k < D_; k += 4) {
        float4 w = *(const float4*)(wrow + k);
        dot += rows[i][k] * w.x + rows[i][k + 1] * w.y + rows[i][k + 2] * w.z + rows[i][k + 3] * w.w;
      }
      agg += (dot + blv) * wts[i * 8 + h3];
    }
    __syncthreads();
  }
  __syncthreads();
  ln_mlp_tail(v, t, agg, prev, bias_gat, g2, b2, Wmlp, bmlp, out, ysh, red);
}

extern "C" void kernel_launch(void* const* d_in, const int* in_sizes, int n_in,
                              void* d_out, int out_size, void* d_ws, size_t ws_size,
                              hipStream_t stream) {
  const float* proj = (const float*)d_in[0];
  const float* prev = (const float*)d_in[1];
  const int* esrc = (const int*)d_in[2];
  const int* edst = (const int*)d_in[3];
  const float* Wl = (const float*)d_in[4];
  const float* bl = (const float*)d_in[5];
  const float* Wr = (const float*)d_in[6];
  const float* br = (const float*)d_in[7];
  const float* att = (const float*)d_in[8];
  const float* bias_gat = (const float*)d_in[9];
  const float* g1 = (const float*)d_in[10];
  const float* b1 = (const float*)d_in[11];
  const float* g2 = (const float*)d_in[12];
  const float* b2 = (const float*)d_in[13];
  const float* Wmlp = (const float*)d_in[14];
  const float* bmlp = (const float*)d_in[15];
  float* out = (float*)d_out;

  char* p = (char*)d_ws;
  size_t off = 0;
  auto carve = [&](size_t bytes) -> char* {
    char* q = p + off;
    off += (bytes + 255) & ~(size_t)255;
    return q;
  };
  float* xr = (float*)carve((size_t)NV_ * D_ * 4);
  float* logitsA = (float*)carve((size_t)NP_ * H_ * 4);
  int* cnt = (int*)carve((size_t)NV_ * 4);
  int* offs = (int*)carve((size_t)(NV_ + 1) * 4);
  int* cursor = (int*)carve((size_t)NV_ * 4);
  int* elist = (int*)carve((size_t)NP_ * 4);
  unsigned short* wsB = (unsigned short*)carve((size_t)8 * 8192 * 2);
  unsigned short* xl = (unsigned short*)carve((size_t)NP_ * D_ * 2);
  const bool fast = ws_size >= off;

  k_init<<<(NV_ + 255) / 256, 256, 0, stream>>>(cnt);
  k_prep<<<32, 256, 0, stream>>>(Wl, wsB);
  k_view<<<NV_, 256, 0, stream>>>(prev, Wr, br, g1, b1, xr);
  k_gemm<<<NP_ / 64, 256, 0, stream>>>(proj, wsB, bl, att, edst, xr,
                                       fast ? xl : (unsigned short*)nullptr, logitsA, cnt);
  k_scan<<<1, 256, 0, stream>>>(cnt, offs, cursor);
  k_scatter<<<(NP_ + 255) / 256, 256, 0, stream>>>(edst, cursor, elist);
  if (fast) {
    k_aggmlp<<<NV_, 256, 0, stream>>>(xl, logitsA, offs, elist, prev, bias_gat,
                                      g2, b2, Wmlp, bmlp, out);
  } else {
    k_aggmlp_slow<<<NV_, 256, 0, stream>>>(proj, Wl, bl, esrc, logitsA, offs, elist,
                                           prev, bias_gat, g2, b2, Wmlp, bmlp, out);
  }
}